// Round 1
// baseline (513.278 us; speedup 1.0000x reference)
//
#include <hip/hip_runtime.h>
#include <hip/hip_fp16.h>
#include <cstdint>

// ---------- types ----------
typedef _Float16 half8 __attribute__((ext_vector_type(8)));
typedef _Float16 half4 __attribute__((ext_vector_type(4)));
typedef float floatx4 __attribute__((ext_vector_type(4)));

#define S_TOT 8192
#define H_DIM 1152
#define NHEAD 16
#define HD 72
#define HDP 96      // padded head dim (zeros in 72..95)
#define NSEG 8
#define SEGL 1024
#define SCALE 0.11785113019775793f  // 72^-0.5

// async global->LDS 16B (wave-uniform LDS base + lane*16; our lane offsets are linear in tid)
__device__ __forceinline__ void gld_lds16(const void* g, void* l) {
  __builtin_amdgcn_global_load_lds((const __attribute__((address_space(1))) void*)g,
                                   (__attribute__((address_space(3))) void*)l, 16, 0, 0);
}

// ---------- elementwise cast fp32 -> f16 ----------
__global__ void cast_f32_f16(const float* __restrict__ in, _Float16* __restrict__ out, int n) {
  int i = (blockIdx.x * 256 + threadIdx.x) * 4;
  if (i < n) {
    float4 v = *(const float4*)(in + i);
    half4 o = { (_Float16)v.x, (_Float16)v.y, (_Float16)v.z, (_Float16)v.w };
    *(half4*)(out + i) = o;
  }
}

// ---------- transpose + cast: W[R][C] fp32 -> Wt[C][R] f16 ----------
__global__ void transpose_cast(const float* __restrict__ W, _Float16* __restrict__ Wt,
                               int R, int C) {
  __shared__ float tile[32][33];
  int tx = threadIdx.x, ty = threadIdx.y;          // (32,8)
  int bx = blockIdx.x, by = blockIdx.y;            // col tile, row tile
#pragma unroll
  for (int i = 0; i < 4; ++i)
    tile[ty + i * 8][tx] = W[(size_t)(by * 32 + ty + i * 8) * C + bx * 32 + tx];
  __syncthreads();
#pragma unroll
  for (int i = 0; i < 4; ++i)
    Wt[(size_t)(bx * 32 + ty + i * 8) * R + by * 32 + tx] = (_Float16)tile[tx][ty + i * 8];
}

// ---------- GEMM: C[M][N] = A[M][K] @ Bt[N][K]^T + bias  (m97-style, f16 MFMA) ----------
// M,N multiples of 128; K multiple of 32. 256 threads, 4 waves in 2x2 quadrants of 64.
template <bool OUT_HALF>
__global__ __launch_bounds__(256) void gemm_bt(
    const _Float16* __restrict__ A, const _Float16* __restrict__ Bt,
    const float* __restrict__ bias, float* __restrict__ Cf, _Float16* __restrict__ Ch,
    int M, int N, int K) {
  __shared__ _Float16 As[128 * 32];
  __shared__ _Float16 Bs[128 * 32];
  const int tid = threadIdx.x;
  const int lane = tid & 63, w = tid >> 6;
  const int quad = lane >> 4, l16 = lane & 15;
  const int wm = w >> 1, wn = w & 1;
  const int m0 = blockIdx.y * 128, n0 = blockIdx.x * 128;

  floatx4 acc[4][4] = {};

  for (int kt = 0; kt < K; kt += 32) {
    __syncthreads();
#pragma unroll
    for (int i = 0; i < 2; ++i) {
      int off = tid * 16 + i * 4096;         // byte offset within 128x64B tile
      int row = off >> 6, colb = off & 63;
      gld_lds16((const char*)(A + (size_t)(m0 + row) * K + kt) + colb, (char*)As + off);
      gld_lds16((const char*)(Bt + (size_t)(n0 + row) * K + kt) + colb, (char*)Bs + off);
    }
    __syncthreads();
    half8 af[4], bf[4];
#pragma unroll
    for (int im = 0; im < 4; ++im)
      af[im] = *(const half8*)&As[(wm * 64 + im * 16 + l16) * 32 + quad * 8];
#pragma unroll
    for (int in = 0; in < 4; ++in)
      bf[in] = *(const half8*)&Bs[(wn * 64 + in * 16 + l16) * 32 + quad * 8];
#pragma unroll
    for (int im = 0; im < 4; ++im)
#pragma unroll
      for (int in = 0; in < 4; ++in)
        acc[im][in] = __builtin_amdgcn_mfma_f32_16x16x32_f16(af[im], bf[in], acc[im][in], 0, 0, 0);
  }
  // epilogue: C/D layout col = l16, row = quad*4 + r
#pragma unroll
  for (int im = 0; im < 4; ++im) {
    int m = m0 + wm * 64 + im * 16 + quad * 4;
#pragma unroll
    for (int in = 0; in < 4; ++in) {
      int n = n0 + wn * 64 + in * 16 + l16;
      float b = bias[n];
#pragma unroll
      for (int r = 0; r < 4; ++r) {
        float v = acc[im][in][r] + b;
        if (OUT_HALF) Ch[(size_t)(m + r) * N + n] = (_Float16)v;
        else          Cf[(size_t)(m + r) * N + n] = v;
      }
    }
  }
}

// ---------- RoPE + scatter to [seg*NH][L][HDP] f16, Q pre-scaled by SCALE ----------
__global__ void rope_scatter(const _Float16* __restrict__ QKV,  // [S][3456]
                             const float* __restrict__ cosb,    // [S][72]
                             const float* __restrict__ sinb,
                             _Float16* __restrict__ Qo, _Float16* __restrict__ Ko,
                             _Float16* __restrict__ Vo) {
  int t = blockIdx.x * 256 + threadIdx.x;  // 0..131071  (s,h)
  int s = t >> 4, h = t & 15;
  int n = s >> 10, l = s & 1023;
  const _Float16* q = QKV + (size_t)s * 3456 + h * HD;
  const _Float16* k = q + H_DIM;
  const _Float16* v = q + 2 * H_DIM;
  const float* cs = cosb + (size_t)s * HD;
  const float* sn = sinb + (size_t)s * HD;
  size_t oo = (((size_t)(n * NHEAD + h)) * SEGL + l) * HDP;
#pragma unroll
  for (int d = 0; d < 36; ++d) {
    float qa = (float)q[d], qb2 = (float)q[d + 36];
    float ka = (float)k[d], kb2 = (float)k[d + 36];
    float c0 = cs[d], s0 = sn[d], c1 = cs[d + 36], s1 = sn[d + 36];
    Qo[oo + d]      = (_Float16)((qa * c0 - qb2 * s0) * SCALE);
    Qo[oo + d + 36] = (_Float16)((qb2 * c1 + qa * s1) * SCALE);
    Ko[oo + d]      = (_Float16)(ka * c0 - kb2 * s0);
    Ko[oo + d + 36] = (_Float16)(kb2 * c1 + ka * s1);
  }
#pragma unroll
  for (int d = 0; d < 72; ++d) Vo[oo + d] = v[d];
#pragma unroll
  for (int d = 72; d < 96; ++d) { Qo[oo + d] = (_Float16)0.f; Ko[oo + d] = (_Float16)0.f; Vo[oo + d] = (_Float16)0.f; }
}

// ---------- flash attention: block = (qb,h,n), 64 q-rows, 4 waves x 16 rows ----------
__global__ __launch_bounds__(256) void attn_kernel(
    const _Float16* __restrict__ Qb, const _Float16* __restrict__ Kb,
    const _Float16* __restrict__ Vb, _Float16* __restrict__ Ctx) {
  __shared__ _Float16 Kt[64 * HDP];      // [key][d]
  __shared__ _Float16 Vt[HDP * 64];      // [d][key]  (transposed)
  __shared__ _Float16 Ps[4][16 * 64];    // per-wave P tile [q][key]
  const int tid = threadIdx.x;
  const int lane = tid & 63, w = tid >> 6;
  const int quad = lane >> 4, l16 = lane & 15;
  const int qb = blockIdx.x, h = blockIdx.y, n = blockIdx.z;
  const size_t headoff = ((size_t)(n * NHEAD + h)) * SEGL * HDP;
  const _Float16* Qg = Qb + headoff;
  const _Float16* Kg = Kb + headoff;
  const _Float16* Vg = Vb + headoff;

  // Q fragments (A-layout: m=l16, k=quad*8+j), kept in registers for whole kernel
  half8 qf[3];
  {
    int row = qb * 64 + w * 16 + l16;
#pragma unroll
    for (int kc = 0; kc < 3; ++kc)
      qf[kc] = *(const half8*)(Qg + (size_t)row * HDP + kc * 32 + quad * 8);
  }
  float m_r[4], l_r[4];
  floatx4 o_acc[6] = {};
#pragma unroll
  for (int r = 0; r < 4; ++r) { m_r[r] = -1e30f; l_r[r] = 0.f; }

  for (int kb = 0; kb < SEGL / 64; ++kb) {
    __syncthreads();
    // K tile: contiguous 64*96*2 = 12288 B in global
    {
      const char* base = (const char*)(Kg + (size_t)kb * 64 * HDP);
#pragma unroll
      for (int i = 0; i < 3; ++i) {
        int off = tid * 16 + i * 4096;
        gld_lds16(base + off, (char*)Kt + off);
      }
    }
    // V tile, transposed into Vt[d][key]; wave w handles d-groups w*3..w*3+2, lane = key
    {
#pragma unroll
      for (int i = 0; i < 3; ++i) {
        int dg = w * 3 + i;
        half8 v = *(const half8*)(Vg + (size_t)(kb * 64 + lane) * HDP + dg * 8);
#pragma unroll
        for (int j = 0; j < 8; ++j) Vt[(dg * 8 + j) * 64 + lane] = v[j];
      }
    }
    __syncthreads();
    // S = Q K^T  (D[q][key]: col=key=l16+16*nt, row=quad*4+r)
    floatx4 s_acc[4];
#pragma unroll
    for (int nt = 0; nt < 4; ++nt) {
      floatx4 a = {};
#pragma unroll
      for (int kc = 0; kc < 3; ++kc) {
        half8 bf = *(const half8*)&Kt[(nt * 16 + l16) * HDP + kc * 32 + quad * 8];
        a = __builtin_amdgcn_mfma_f32_16x16x32_f16(qf[kc], bf, a, 0, 0, 0);
      }
      s_acc[nt] = a;
    }
    // online softmax per row (quad's 16 lanes hold 64 keys of rows quad*4..+3)
#pragma unroll
    for (int r = 0; r < 4; ++r) {
      float mx = fmaxf(fmaxf(s_acc[0][r], s_acc[1][r]), fmaxf(s_acc[2][r], s_acc[3][r]));
#pragma unroll
      for (int off = 8; off >= 1; off >>= 1) mx = fmaxf(mx, __shfl_xor(mx, off, 64));
      float mnew = fmaxf(m_r[r], mx);
      float alpha = __expf(m_r[r] - mnew);
      float sum = 0.f;
#pragma unroll
      for (int nt = 0; nt < 4; ++nt) {
        float p = __expf(s_acc[nt][r] - mnew);
        s_acc[nt][r] = p;
        sum += p;
      }
#pragma unroll
      for (int off = 8; off >= 1; off >>= 1) sum += __shfl_xor(sum, off, 64);
      l_r[r] = l_r[r] * alpha + sum;
      m_r[r] = mnew;
#pragma unroll
      for (int t = 0; t < 6; ++t) o_acc[t][r] *= alpha;
    }
    // P: C-layout -> A-layout via LDS (wave-private region)
    _Float16* Pw = Ps[w];
#pragma unroll
    for (int nt = 0; nt < 4; ++nt)
#pragma unroll
      for (int r = 0; r < 4; ++r)
        Pw[(quad * 4 + r) * 64 + nt * 16 + l16] = (_Float16)s_acc[nt][r];
    __syncthreads();
    // O += P V   (A: P[q=l16][key], B: Vt as [d][key] "Bt" form)
#pragma unroll
    for (int kc2 = 0; kc2 < 2; ++kc2) {
      half8 pa = *(const half8*)&Pw[l16 * 64 + kc2 * 32 + quad * 8];
#pragma unroll
      for (int t = 0; t < 6; ++t) {
        half8 vf = *(const half8*)&Vt[(t * 16 + l16) * 64 + kc2 * 32 + quad * 8];
        o_acc[t] = __builtin_amdgcn_mfma_f32_16x16x32_f16(pa, vf, o_acc[t], 0, 0, 0);
      }
    }
  }
  // epilogue: ctx[s][h*72+d] = o/l  (skip padded d>=72)
  const int qrow0 = qb * 64 + w * 16 + quad * 4;
#pragma unroll
  for (int t = 0; t < 6; ++t) {
    int d = t * 16 + l16;
    if (d < HD) {
#pragma unroll
      for (int r = 0; r < 4; ++r) {
        int s = n * SEGL + qrow0 + r;
        Ctx[(size_t)s * H_DIM + h * HD + d] = (_Float16)(o_acc[t][r] / l_r[r]);
      }
    }
  }
}

extern "C" void kernel_launch(void* const* d_in, const int* in_sizes, int n_in,
                              void* d_out, int out_size, void* d_ws, size_t ws_size,
                              hipStream_t stream) {
  const float* X    = (const float*)d_in[0];   // [1,8192,1152]
  const float* cosb = (const float*)d_in[1];   // [8192,72]
  const float* sinb = (const float*)d_in[2];
  const float* Wqkv = (const float*)d_in[3];   // [1152,3456]
  const float* bqkv = (const float*)d_in[4];
  const float* Wout = (const float*)d_in[5];   // [1152,1152]
  const float* bout = (const float*)d_in[6];
  // d_in[7] = cu_seqlens (fixed equal segments; unused)
  float* out = (float*)d_out;
  char* ws = (char*)d_ws;

  _Float16* Xb   = (_Float16*)(ws);              // 8192*1152*2   = 18874368
  _Float16* Wqt  = (_Float16*)(ws + 18874368);   // 3456*1152*2   =  7962624
  _Float16* Wot  = (_Float16*)(ws + 26836992);   // 1152*1152*2   =  2654208
  _Float16* QKVb = (_Float16*)(ws + 29491200);   // 8192*3456*2   = 56623104
  _Float16* Qb   = (_Float16*)(ws + 86114304);   // 128*1024*96*2 = 25165824
  _Float16* Kb   = (_Float16*)(ws + 111280128);
  _Float16* Vb   = (_Float16*)(ws + 136445952);
  _Float16* Ctx  = (_Float16*)(ws + 161611776);  // 8192*1152*2   = 18874368  -> total 180486144 B

  cast_f32_f16<<<9216, 256, 0, stream>>>(X, Xb, S_TOT * H_DIM);
  transpose_cast<<<dim3(108, 36), dim3(32, 8), 0, stream>>>(Wqkv, Wqt, H_DIM, 3 * H_DIM);
  transpose_cast<<<dim3(36, 36), dim3(32, 8), 0, stream>>>(Wout, Wot, H_DIM, H_DIM);
  gemm_bt<true><<<dim3(27, 64), 256, 0, stream>>>(Xb, Wqt, bqkv, nullptr, QKVb,
                                                  S_TOT, 3 * H_DIM, H_DIM);
  rope_scatter<<<512, 256, 0, stream>>>(QKVb, cosb, sinb, Qb, Kb, Vb);
  attn_kernel<<<dim3(16, 16, 8), 256, 0, stream>>>(Qb, Kb, Vb, Ctx);
  gemm_bt<false><<<dim3(9, 64), 256, 0, stream>>>(Ctx, Wot, bout, out, nullptr,
                                                  S_TOT, H_DIM, H_DIM);
}

// Round 2
// 432.807 us; speedup vs baseline: 1.1859x; 1.1859x over previous
//
#include <hip/hip_runtime.h>
#include <hip/hip_fp16.h>
#include <cstdint>

// ---------- types ----------
typedef _Float16 half8 __attribute__((ext_vector_type(8)));
typedef _Float16 half4 __attribute__((ext_vector_type(4)));
typedef float floatx4 __attribute__((ext_vector_type(4)));

#define S_TOT 8192
#define H_DIM 1152
#define NHEAD 16
#define HD 72
#define HDP 96      // padded head dim (zeros in 72..95)
#define NSEG 8
#define SEGL 1024
// 72^-0.5 * log2(e): exp2-based softmax, scale folded into Q
#define QSCALE 0.17002324631230988f

// async global->LDS 16B (wave-uniform LDS base + lane*16)
__device__ __forceinline__ void gld_lds16(const void* g, void* l) {
  __builtin_amdgcn_global_load_lds((const __attribute__((address_space(1))) void*)g,
                                   (__attribute__((address_space(3))) void*)l, 16, 0, 0);
}

// ---------- elementwise cast fp32 -> f16 ----------
__global__ void cast_f32_f16(const float* __restrict__ in, _Float16* __restrict__ out, int n) {
  int i = (blockIdx.x * 256 + threadIdx.x) * 4;
  if (i < n) {
    float4 v = *(const float4*)(in + i);
    half4 o = { (_Float16)v.x, (_Float16)v.y, (_Float16)v.z, (_Float16)v.w };
    *(half4*)(out + i) = o;
  }
}

// ---------- transpose + cast: W[R][C] fp32 -> Wt[C][R] f16 ----------
__global__ void transpose_cast(const float* __restrict__ W, _Float16* __restrict__ Wt,
                               int R, int C) {
  __shared__ float tile[32][33];
  int tx = threadIdx.x, ty = threadIdx.y;          // (32,8)
  int bx = blockIdx.x, by = blockIdx.y;
#pragma unroll
  for (int i = 0; i < 4; ++i)
    tile[ty + i * 8][tx] = W[(size_t)(by * 32 + ty + i * 8) * C + bx * 32 + tx];
  __syncthreads();
#pragma unroll
  for (int i = 0; i < 4; ++i)
    Wt[(size_t)(bx * 32 + ty + i * 8) * R + by * 32 + tx] = (_Float16)tile[tx][ty + i * 8];
}

// ---------- GEMM: C[M][N] = A[M][K] @ Bt[N][K]^T + bias  (m97-style, f16 MFMA) ----------
template <bool OUT_HALF>
__global__ __launch_bounds__(256) void gemm_bt(
    const _Float16* __restrict__ A, const _Float16* __restrict__ Bt,
    const float* __restrict__ bias, float* __restrict__ Cf, _Float16* __restrict__ Ch,
    int M, int N, int K) {
  __shared__ _Float16 As[128 * 32];
  __shared__ _Float16 Bs[128 * 32];
  const int tid = threadIdx.x;
  const int lane = tid & 63, w = tid >> 6;
  const int quad = lane >> 4, l16 = lane & 15;
  const int wm = w >> 1, wn = w & 1;
  const int m0 = blockIdx.y * 128, n0 = blockIdx.x * 128;

  floatx4 acc[4][4] = {};

  for (int kt = 0; kt < K; kt += 32) {
    __syncthreads();
#pragma unroll
    for (int i = 0; i < 2; ++i) {
      int off = tid * 16 + i * 4096;
      int row = off >> 6, colb = off & 63;
      gld_lds16((const char*)(A + (size_t)(m0 + row) * K + kt) + colb, (char*)As + off);
      gld_lds16((const char*)(Bt + (size_t)(n0 + row) * K + kt) + colb, (char*)Bs + off);
    }
    __syncthreads();
    half8 af[4], bf[4];
#pragma unroll
    for (int im = 0; im < 4; ++im)
      af[im] = *(const half8*)&As[(wm * 64 + im * 16 + l16) * 32 + quad * 8];
#pragma unroll
    for (int in = 0; in < 4; ++in)
      bf[in] = *(const half8*)&Bs[(wn * 64 + in * 16 + l16) * 32 + quad * 8];
#pragma unroll
    for (int im = 0; im < 4; ++im)
#pragma unroll
      for (int in = 0; in < 4; ++in)
        acc[im][in] = __builtin_amdgcn_mfma_f32_16x16x32_f16(af[im], bf[in], acc[im][in], 0, 0, 0);
  }
#pragma unroll
  for (int im = 0; im < 4; ++im) {
    int m = m0 + wm * 64 + im * 16 + quad * 4;
#pragma unroll
    for (int in = 0; in < 4; ++in) {
      int n = n0 + wn * 64 + in * 16 + l16;
      float b = bias[n];
#pragma unroll
      for (int r = 0; r < 4; ++r) {
        float v = acc[im][in][r] + b;
        if (OUT_HALF) Ch[(size_t)(m + r) * N + n] = (_Float16)v;
        else          Cf[(size_t)(m + r) * N + n] = v;
      }
    }
  }
}

// ---------- RoPE + scatter to [seg*NH][L][HDP] f16 (vectorized), Q pre-scaled ----------
__global__ void rope_scatter(const _Float16* __restrict__ QKV,  // [S][3456]
                             const float* __restrict__ cosb,    // [S][72]
                             const float* __restrict__ sinb,
                             _Float16* __restrict__ Qo, _Float16* __restrict__ Ko,
                             _Float16* __restrict__ Vo) {
  int t = blockIdx.x * 256 + threadIdx.x;  // (s,h)
  int s = t >> 4, h = t & 15;
  int n = s >> 10, l = s & 1023;
  const _Float16* q = QKV + (size_t)s * 3456 + h * HD;
  const _Float16* k = q + H_DIM;
  const _Float16* v = q + 2 * H_DIM;
  const float* cs = cosb + (size_t)s * HD;
  const float* sn = sinb + (size_t)s * HD;
  size_t oo = (((size_t)(n * NHEAD + h)) * SEGL + l) * HDP;
  half8 z = {};
  // Q
  {
    _Float16 qr[72], qo[72];
#pragma unroll
    for (int i = 0; i < 9; ++i) *(half8*)&qr[8 * i] = *(const half8*)(q + 8 * i);
#pragma unroll
    for (int d = 0; d < 36; ++d) {
      float c0 = cs[d], s0 = sn[d], c1 = cs[d + 36], s1 = sn[d + 36];
      float a = (float)qr[d], b = (float)qr[d + 36];
      qo[d]      = (_Float16)((a * c0 - b * s0) * QSCALE);
      qo[d + 36] = (_Float16)((b * c1 + a * s1) * QSCALE);
    }
#pragma unroll
    for (int i = 0; i < 9; ++i) *(half8*)(Qo + oo + 8 * i) = *(half8*)&qo[8 * i];
#pragma unroll
    for (int i = 9; i < 12; ++i) *(half8*)(Qo + oo + 8 * i) = z;
  }
  // K
  {
    _Float16 kr[72], ko[72];
#pragma unroll
    for (int i = 0; i < 9; ++i) *(half8*)&kr[8 * i] = *(const half8*)(k + 8 * i);
#pragma unroll
    for (int d = 0; d < 36; ++d) {
      float c0 = cs[d], s0 = sn[d], c1 = cs[d + 36], s1 = sn[d + 36];
      float a = (float)kr[d], b = (float)kr[d + 36];
      ko[d]      = (_Float16)(a * c0 - b * s0);
      ko[d + 36] = (_Float16)(b * c1 + a * s1);
    }
#pragma unroll
    for (int i = 0; i < 9; ++i) *(half8*)(Ko + oo + 8 * i) = *(half8*)&ko[8 * i];
#pragma unroll
    for (int i = 9; i < 12; ++i) *(half8*)(Ko + oo + 8 * i) = z;
  }
  // V
#pragma unroll
  for (int i = 0; i < 9; ++i) *(half8*)(Vo + oo + 8 * i) = *(const half8*)(v + 8 * i);
#pragma unroll
  for (int i = 9; i < 12; ++i) *(half8*)(Vo + oo + 8 * i) = z;
}

// ---------- flash attention (S^T scheme): block = (qb,h,n), 128 q-rows, 4 waves x 32 q ----------
// S^T = K·Q^T  => lane holds S^T[key=nt*16+quad*4+r][q=l16]: all keys of one q share l16.
// PV as O^T = V^T·P^T: A = Vt[d][key] (stride 72), B = P[q][key] (stride 72).
__global__ __launch_bounds__(256) void attn_kernel(
    const _Float16* __restrict__ Qb, const _Float16* __restrict__ Kb,
    const _Float16* __restrict__ Vb, _Float16* __restrict__ Ctx) {
  __shared__ _Float16 Kt[64 * 96];        // [key][d] (gld_lds linear copy)
  __shared__ _Float16 Vt[80 * 72];        // [d][key], row stride 72 (pad) — only d<80 needed
  __shared__ _Float16 Ps[4 * 32 * 72];    // [wave][q32][key64 pad to 72]
  const int tid = threadIdx.x;
  const int lane = tid & 63, w = tid >> 6;
  const int quad = lane >> 4, l16 = lane & 15;
  const int qb = blockIdx.x, h = blockIdx.y, n = blockIdx.z;
  const size_t headoff = ((size_t)(n * NHEAD + h)) * SEGL * HDP;
  const _Float16* Qg = Qb + headoff;
  const _Float16* Kg = Kb + headoff;
  const _Float16* Vg = Vb + headoff;

  // Q as B-operand fragments: lane holds Q[q=l16][k=quad*8+j]
  half8 qf[2][3];
#pragma unroll
  for (int qg = 0; qg < 2; ++qg) {
    int row = qb * 128 + w * 32 + qg * 16 + l16;
#pragma unroll
    for (int kc = 0; kc < 3; ++kc)
      qf[qg][kc] = *(const half8*)(Qg + (size_t)row * HDP + kc * 32 + quad * 8);
  }
  float m_s[2] = {-1e30f, -1e30f}, l_s[2] = {0.f, 0.f};
  floatx4 o_acc[2][5] = {};   // O^T[d = t*16+quad*4+r][q = l16], t<5 (d<80)

  for (int kb = 0; kb < SEGL / 64; ++kb) {
    __syncthreads();
    // K tile: contiguous 64*96*2 = 12288 B
    {
      const char* base = (const char*)(Kg + (size_t)kb * 64 * HDP);
#pragma unroll
      for (int i = 0; i < 3; ++i) {
        int off = tid * 16 + i * 4096;
        gld_lds16(base + off, (char*)Kt + off);
      }
    }
    // V tile transposed into Vt[d][key], only d<80; lane = key
#pragma unroll
    for (int i = 0; i < 3; ++i) {
      int dg = w * 3 + i;
      if (dg < 10) {
        half8 vv = *(const half8*)(Vg + (size_t)(kb * 64 + lane) * HDP + dg * 8);
#pragma unroll
        for (int j = 0; j < 8; ++j) Vt[(dg * 8 + j) * 72 + lane] = vv[j];
      }
    }
    __syncthreads();
    // S^T = K·Q^T
    floatx4 sa[2][4] = {};
#pragma unroll
    for (int nt = 0; nt < 4; ++nt) {
#pragma unroll
      for (int kc = 0; kc < 3; ++kc) {
        half8 kf = *(const half8*)&Kt[(nt * 16 + l16) * 96 + kc * 32 + quad * 8];
        sa[0][nt] = __builtin_amdgcn_mfma_f32_16x16x32_f16(kf, qf[0][kc], sa[0][nt], 0, 0, 0);
        sa[1][nt] = __builtin_amdgcn_mfma_f32_16x16x32_f16(kf, qf[1][kc], sa[1][nt], 0, 0, 0);
      }
    }
    // online softmax: per-lane column q=l16; reduce in-lane then across quads
#pragma unroll
    for (int qg = 0; qg < 2; ++qg) {
      float mx = -1e30f;
#pragma unroll
      for (int nt = 0; nt < 4; ++nt)
#pragma unroll
        for (int r = 0; r < 4; ++r) mx = fmaxf(mx, sa[qg][nt][r]);
      mx = fmaxf(mx, __shfl_xor(mx, 16, 64));
      mx = fmaxf(mx, __shfl_xor(mx, 32, 64));
      float mnew = fmaxf(m_s[qg], mx);
      float alpha = exp2f(m_s[qg] - mnew);
      float sum = 0.f;
#pragma unroll
      for (int nt = 0; nt < 4; ++nt)
#pragma unroll
        for (int r = 0; r < 4; ++r) {
          float p = exp2f(sa[qg][nt][r] - mnew);
          sa[qg][nt][r] = p;
          sum += p;
        }
      sum += __shfl_xor(sum, 16, 64);
      sum += __shfl_xor(sum, 32, 64);
      l_s[qg] = l_s[qg] * alpha + sum;
      m_s[qg] = mnew;
#pragma unroll
      for (int t = 0; t < 5; ++t) o_acc[qg][t] *= alpha;
      // P store: 4 contiguous keys per write (b64)
      int prow = (w * 32 + qg * 16 + l16) * 72;
#pragma unroll
      for (int nt = 0; nt < 4; ++nt) {
        half4 ph = { (_Float16)sa[qg][nt][0], (_Float16)sa[qg][nt][1],
                     (_Float16)sa[qg][nt][2], (_Float16)sa[qg][nt][3] };
        *(half4*)&Ps[prow + nt * 16 + quad * 4] = ph;
      }
    }
    // O^T += V^T·P^T   (wave-private P, no barrier needed)
#pragma unroll
    for (int kc2 = 0; kc2 < 2; ++kc2) {
      half8 pb0 = *(const half8*)&Ps[(w * 32 + l16) * 72 + kc2 * 32 + quad * 8];
      half8 pb1 = *(const half8*)&Ps[(w * 32 + 16 + l16) * 72 + kc2 * 32 + quad * 8];
#pragma unroll
      for (int t = 0; t < 5; ++t) {
        half8 vf = *(const half8*)&Vt[(t * 16 + l16) * 72 + kc2 * 32 + quad * 8];
        o_acc[0][t] = __builtin_amdgcn_mfma_f32_16x16x32_f16(vf, pb0, o_acc[0][t], 0, 0, 0);
        o_acc[1][t] = __builtin_amdgcn_mfma_f32_16x16x32_f16(vf, pb1, o_acc[1][t], 0, 0, 0);
      }
    }
  }
  // epilogue: lane holds d = t*16+quad*4+r (contiguous r) for q=l16 -> half4 stores
#pragma unroll
  for (int qg = 0; qg < 2; ++qg) {
    float rl = 1.0f / l_s[qg];
    size_t s2 = (size_t)n * SEGL + qb * 128 + w * 32 + qg * 16 + l16;
#pragma unroll
    for (int t = 0; t < 5; ++t) {
      int d0 = t * 16 + quad * 4;
      if (d0 < HD) {
        half4 hv = { (_Float16)(o_acc[qg][t][0] * rl), (_Float16)(o_acc[qg][t][1] * rl),
                     (_Float16)(o_acc[qg][t][2] * rl), (_Float16)(o_acc[qg][t][3] * rl) };
        *(half4*)&Ctx[s2 * H_DIM + h * HD + d0] = hv;
      }
    }
  }
}

extern "C" void kernel_launch(void* const* d_in, const int* in_sizes, int n_in,
                              void* d_out, int out_size, void* d_ws, size_t ws_size,
                              hipStream_t stream) {
  const float* X    = (const float*)d_in[0];
  const float* cosb = (const float*)d_in[1];
  const float* sinb = (const float*)d_in[2];
  const float* Wqkv = (const float*)d_in[3];
  const float* bqkv = (const float*)d_in[4];
  const float* Wout = (const float*)d_in[5];
  const float* bout = (const float*)d_in[6];
  float* out = (float*)d_out;
  char* ws = (char*)d_ws;

  _Float16* Xb   = (_Float16*)(ws);
  _Float16* Wqt  = (_Float16*)(ws + 18874368);
  _Float16* Wot  = (_Float16*)(ws + 26836992);
  _Float16* QKVb = (_Float16*)(ws + 29491200);
  _Float16* Qb   = (_Float16*)(ws + 86114304);
  _Float16* Kb   = (_Float16*)(ws + 111280128);
  _Float16* Vb   = (_Float16*)(ws + 136445952);
  _Float16* Ctx  = (_Float16*)(ws + 161611776);

  cast_f32_f16<<<9216, 256, 0, stream>>>(X, Xb, S_TOT * H_DIM);
  transpose_cast<<<dim3(108, 36), dim3(32, 8), 0, stream>>>(Wqkv, Wqt, H_DIM, 3 * H_DIM);
  transpose_cast<<<dim3(36, 36), dim3(32, 8), 0, stream>>>(Wout, Wot, H_DIM, H_DIM);
  gemm_bt<true><<<dim3(27, 64), 256, 0, stream>>>(Xb, Wqt, bqkv, nullptr, QKVb,
                                                  S_TOT, 3 * H_DIM, H_DIM);
  rope_scatter<<<512, 256, 0, stream>>>(QKVb, cosb, sinb, Qb, Kb, Vb);
  attn_kernel<<<dim3(8, 16, 8), 256, 0, stream>>>(Qb, Kb, Vb, Ctx);
  gemm_bt<false><<<dim3(9, 64), 256, 0, stream>>>(Ctx, Wot, bout, out, nullptr,
                                                  S_TOT, H_DIM, H_DIM);
}